// Round 9
// baseline (313.802 us; speedup 1.0000x reference)
//
#include <hip/hip_runtime.h>

// SwitchGNN split pipeline (R8 + L3-resident chunk hand-off):
//  out = (1/7) * sum_t [ (segsum_t(x[src]) / max(cnt,1)) @ W_t + 1{cnt>0} b_t ]
// P0 convx_k: x -> bf16 rows (256B each); halves gather payload
// P1 wconv_k: W -> bf16, transposed [t][f][k], XOR-swizzled (GEMM B operand)
// P2 fill_k : bucket edges by (dst,type), XCD-partitioned dst ranges
// per 32768-node chunk (aggb chunk 58.7MB reused each pass -> stays in L3,
// so agg writes and gemm A-reads never round-trip HBM):
// P3 agg_k  : one wave per node, all 7 types, 2-type x 2-edge (4 chains)
// P4 gemm_k : 128-row tiles, 8 waves, K=7x128, global_load_lds(16B),
//             mfma_f32_16x16x32_bf16, bias+mean epilogue.

constexpr int NN = 100000;
constexpr int NT = 7;
constexpr int NE = 250000;
constexpr int DD = 128;
constexpr int CAP = 20;           // max tracked edges per (n,t); P(Poisson(2.5)>20)~3e-12
constexpr int OVF = CAP - 8;      // overflow slots beyond the 8 fast slots
constexpr int NROWS = ((NN + 127) / 128) * 128;   // 100096 padded rows
constexpr int NPART = 8;                          // dst partitions = XCDs
constexpr int PSIZE = (NN + NPART - 1) / NPART;   // 12500 nodes per partition
constexpr int EPB = 1024;                         // edges per fill block
constexpr int NSLAB = (NE + EPB - 1) / EPB;       // 245 slabs
constexpr int NCMAX = 32768;                      // chunk rows: 58.7MB -> L3-resident

typedef short bf16x8 __attribute__((ext_vector_type(8)));
typedef float f32x4 __attribute__((ext_vector_type(4)));

__device__ __forceinline__ unsigned pack_bf16x2(float lo, float hi) {
    unsigned a = __float_as_uint(lo), b = __float_as_uint(hi);
    unsigned al = (a + 0x7FFFu + ((a >> 16) & 1u)) >> 16;          // RNE
    unsigned bh = (b + 0x7FFFu + ((b >> 16) & 1u)) & 0xFFFF0000u;
    return al | bh;
}

// ---------------------------------------------------------------- conv x ----
__global__ __launch_bounds__(256) void convx_k(
    const float* __restrict__ x, uint4* __restrict__ xb)
{
    int id = blockIdx.x * 256 + threadIdx.x;
    const float4* src = (const float4*)x;
    float4 v0 = src[(size_t)id * 2];
    float4 v1 = src[(size_t)id * 2 + 1];
    uint4 o;
    o.x = pack_bf16x2(v0.x, v0.y);
    o.y = pack_bf16x2(v0.z, v0.w);
    o.z = pack_bf16x2(v1.x, v1.y);
    o.w = pack_bf16x2(v1.z, v1.w);
    xb[id] = o;
}

// ---------------------------------------------------------------- W conv ----
// WTb[t][f][k] bf16, row=256B, granule ^= f&7. One wave per (t,f).
__global__ __launch_bounds__(256) void wconv_k(
    const float* __restrict__ W, char* __restrict__ WTb)
{
    int wid = (blockIdx.x * 256 + threadIdx.x) >> 6;
    int lane = threadIdx.x & 63;
    int t = wid >> 7, f = wid & 127;
    if (t >= NT) return;
    const float* Wt = W + (size_t)t * DD * DD;
    float w0 = Wt[(size_t)(2 * lane) * DD + f];
    float w1 = Wt[(size_t)(2 * lane + 1) * DD + f];
    int gran = (lane >> 2) ^ (f & 7);
    *(unsigned*)(WTb + (size_t)t * 32768 + f * 256 + gran * 16 + (lane & 3) * 4)
        = pack_bf16x2(w0, w1);
}

// ------------------------------------------------------------------ fill ----
// blockIdx.x = slab*8 + partition; keep only edges whose dst is in this
// partition's 1/8 range so each XCD's bucket writes stay L2-resident.
__global__ __launch_bounds__(256) void fill_k(
    const int* __restrict__ ei,      // [NT][2][NE]
    int* __restrict__ cnt,           // [NN][NT], zeroed
    int* __restrict__ eidx8,         // [NN][NT][8]
    int* __restrict__ ovf)           // [NT][NN][OVF]
{
    int part = blockIdx.x & (NPART - 1);
    int slab = blockIdx.x >> 3;
    int t = blockIdx.y;
    int e0 = slab * EPB + threadIdx.x * 4;
    if (e0 >= NE) return;
    const int* p = ei + (size_t)t * 2 * NE;
    int4 s4 = *(const int4*)(p + e0);        // NE % 4 == 0: in-bounds
    int4 d4 = *(const int4*)(p + NE + e0);
    int lo = part * PSIZE;
    int hi = lo + PSIZE;
    #pragma unroll
    for (int k = 0; k < 4; ++k) {
        int src = k == 0 ? s4.x : k == 1 ? s4.y : k == 2 ? s4.z : s4.w;
        int dst = k == 0 ? d4.x : k == 1 ? d4.y : k == 2 ? d4.z : d4.w;
        if (dst >= lo && dst < hi) {
            int pos = atomicAdd(cnt + (size_t)dst * NT + t, 1);
            if (pos < 8)        eidx8[((size_t)dst * NT + t) * 8 + pos] = src;
            else if (pos < CAP) ovf[((size_t)t * NN + dst) * OVF + (pos - 8)] = src;
        }
    }
}

// ------------------------------------------------------------- aggregate ----
// One wave per chunk row (node n = c0 + wid). Lanes 0..6: per-type counts;
// lanes 0..55: fast-slot indices. 2 types x 2 edges = 4 gather chains in
// flight. Lane holds features 2*lane, 2*lane+1. Rows n >= NN write zeros.
__global__ __launch_bounds__(256) void agg_k(
    const char* __restrict__ xb,     // [NN][256B] bf16 rows
    const int* __restrict__ cnt,     // [NN][NT]
    const int* __restrict__ eidx8,   // [NN][NT][8]
    const int* __restrict__ ovf,     // [NT][NN][OVF]
    char* __restrict__ aggb,         // [NT][nc][256B] chunk, swizzled
    int c0, int nc)
{
    int wid = (blockIdx.x * 256 + threadIdx.x) >> 6;
    int lane = threadIdx.x & 63;
    if (wid >= nc) return;
    const int n = c0 + wid;
    const bool live = (n < NN);

    int cntv = (live && lane < NT) ? cnt[(size_t)n * NT + lane] : 0;
    int idxv = (live && lane < 56) ? eidx8[(size_t)n * 56 + lane] : 0;

    int r = wid & 127;
    int gran = (lane >> 2) ^ (r & 7);            // swizzle for ds_read_b128
    char* wbase = aggb + (size_t)(wid >> 7) * 32768 + r * 256
                + gran * 16 + (lane & 3) * 4;
    const size_t tstride = (size_t)nc * 256;

    for (int tp = 0; tp < NT; tp += 2) {
        int cA = __shfl(cntv, tp);
        int cB = (tp + 1 < NT) ? __shfl(cntv, tp + 1) : 0;
        int ccA = cA < CAP ? cA : CAP;
        int ccB = cB < CAP ? cB : CAP;
        int m = ccA > ccB ? ccA : ccB;

        float a0 = 0.f, a1 = 0.f, b0 = 0.f, b1 = 0.f;
        for (int e = 0; e < m; e += 2) {         // 4 chains: 2 types x 2 edges
            unsigned vA0 = 0, vA1 = 0, vB0 = 0, vB1 = 0;
            bool gA0 = e < ccA, gA1 = e + 1 < ccA;
            bool gB0 = e < ccB, gB1 = e + 1 < ccB;
            if (gA0) {
                int s = (e < 8) ? __shfl(idxv, tp * 8 + e)
                                : ovf[((size_t)tp * NN + n) * OVF + (e - 8)];
                vA0 = *(const unsigned*)(xb + (size_t)s * 256 + lane * 4);
            }
            if (gA1) {
                int s = (e + 1 < 8) ? __shfl(idxv, tp * 8 + e + 1)
                                    : ovf[((size_t)tp * NN + n) * OVF + (e - 7)];
                vA1 = *(const unsigned*)(xb + (size_t)s * 256 + lane * 4);
            }
            if (gB0) {
                int s = (e < 8) ? __shfl(idxv, (tp + 1) * 8 + e)
                                : ovf[((size_t)(tp + 1) * NN + n) * OVF + (e - 8)];
                vB0 = *(const unsigned*)(xb + (size_t)s * 256 + lane * 4);
            }
            if (gB1) {
                int s = (e + 1 < 8) ? __shfl(idxv, (tp + 1) * 8 + e + 1)
                                    : ovf[((size_t)(tp + 1) * NN + n) * OVF + (e - 7)];
                vB1 = *(const unsigned*)(xb + (size_t)s * 256 + lane * 4);
            }
            a0 += __uint_as_float(vA0 << 16) + __uint_as_float(vA1 << 16);
            a1 += __uint_as_float(vA0 & 0xFFFF0000u) + __uint_as_float(vA1 & 0xFFFF0000u);
            b0 += __uint_as_float(vB0 << 16) + __uint_as_float(vB1 << 16);
            b1 += __uint_as_float(vB0 & 0xFFFF0000u) + __uint_as_float(vB1 & 0xFFFF0000u);
        }
        float sa = 1.0f / fmaxf((float)cA, 1.0f);   // mean folded pre-GEMM
        *(unsigned*)(wbase + (size_t)tp * tstride) = pack_bf16x2(a0 * sa, a1 * sa);
        if (tp + 1 < NT) {
            float sb = 1.0f / fmaxf((float)cB, 1.0f);
            *(unsigned*)(wbase + (size_t)(tp + 1) * tstride) = pack_bf16x2(b0 * sb, b1 * sb);
        }
    }
}

// ------------------------------------------------------------------ gemm ----
// 512 threads = 8 waves; wave w=(wy,wx): rows wy*32..+31, cols wx*64..+63.
// K-loop over 7 types (K=896, BK=128). Rows are chunk-local.
__global__ __launch_bounds__(512) void gemm_k(
    const char* __restrict__ aggb, const char* __restrict__ WTb,
    const int* __restrict__ cnt, const float* __restrict__ bias,
    float* __restrict__ out, int c0, int nc)
{
    __shared__ char sA[128 * 256];   // 32 KB
    __shared__ char sW[128 * 256];   // 32 KB
    int tid = threadIdx.x;
    int w = tid >> 6, lane = tid & 63;
    int wy = w >> 1, wx = w & 1;
    int n0 = c0 + blockIdx.x * 128;
    const size_t tstride = (size_t)nc * 256;

    f32x4 acc[2][4];
    #pragma unroll
    for (int i = 0; i < 2; ++i)
        #pragma unroll
        for (int j = 0; j < 4; ++j) acc[i][j] = (f32x4)0.0f;

    for (int t = 0; t < NT; ++t) {
        __syncthreads();   // prev MFMA readers done before restage
        const char* asrc = aggb + (size_t)t * tstride + (size_t)blockIdx.x * 32768;
        const char* wsrc = WTb + (size_t)t * 32768;
        #pragma unroll
        for (int i = 0; i < 4; ++i) {
            int ch = w * 4 + i;     // 32 chunks x 1KB each
            __builtin_amdgcn_global_load_lds(
                (const __attribute__((address_space(1))) void*)(asrc + ch * 1024 + lane * 16),
                (__attribute__((address_space(3))) void*)(sA + ch * 1024), 16, 0, 0);
            __builtin_amdgcn_global_load_lds(
                (const __attribute__((address_space(1))) void*)(wsrc + ch * 1024 + lane * 16),
                (__attribute__((address_space(3))) void*)(sW + ch * 1024), 16, 0, 0);
        }
        __syncthreads();   // compiler drains vmcnt before barrier

        #pragma unroll
        for (int c = 0; c < 4; ++c) {
            int gsel = ((c * 4 + (lane >> 4)) ^ (lane & 7)) << 4;
            bf16x8 A0 = *(const bf16x8*)(sA + (wy * 32 + (lane & 15)) * 256 + gsel);
            bf16x8 A1 = *(const bf16x8*)(sA + (wy * 32 + 16 + (lane & 15)) * 256 + gsel);
            #pragma unroll
            for (int nj = 0; nj < 4; ++nj) {
                bf16x8 B = *(const bf16x8*)(sW + (wx * 64 + nj * 16 + (lane & 15)) * 256 + gsel);
                acc[0][nj] = __builtin_amdgcn_mfma_f32_16x16x32_bf16(A0, B, acc[0][nj], 0, 0, 0);
                acc[1][nj] = __builtin_amdgcn_mfma_f32_16x16x32_bf16(A1, B, acc[1][nj], 0, 0, 0);
            }
        }
    }

    // epilogue: mean over types + per-type bias where cnt>0
    const float inv7 = 1.0f / (float)NT;
    #pragma unroll
    for (int mi = 0; mi < 2; ++mi) {
        #pragma unroll
        for (int v = 0; v < 4; ++v) {
            int n = n0 + wy * 32 + mi * 16 + (lane >> 4) * 4 + v;
            if (n >= NN) continue;
            float add[4] = {0.f, 0.f, 0.f, 0.f};
            for (int t = 0; t < NT; ++t) {
                if (cnt[(size_t)n * NT + t] > 0) {
                    #pragma unroll
                    for (int nj = 0; nj < 4; ++nj)
                        add[nj] += bias[(size_t)t * DD + wx * 64 + nj * 16 + (lane & 15)];
                }
            }
            #pragma unroll
            for (int nj = 0; nj < 4; ++nj)
                out[(size_t)n * DD + wx * 64 + nj * 16 + (lane & 15)]
                    = inv7 * (acc[mi][nj][v] + add[nj]);
        }
    }
}

// ---------------------------------------------------------------- launch ----
extern "C" void kernel_launch(void* const* d_in, const int* in_sizes, int n_in,
                              void* d_out, int out_size, void* d_ws, size_t ws_size,
                              hipStream_t stream) {
    const float* x  = (const float*)d_in[0];
    const int*   ei = (const int*)d_in[1];
    const float* W  = (const float*)d_in[2];
    const float* b  = (const float*)d_in[3];
    float* out = (float*)d_out;
    char* ws = (char*)d_ws;

    // fixed tables: 84.7 MB (layout proven R6/R8)
    size_t off = 0;
    char* xb    = ws + off; off += (size_t)NN * 256;                  // 25.6 MB
    char* WTb   = ws + off; off += (size_t)NT * 128 * 256;            // 224 KB
    int*  eidx8 = (int*)(ws + off); off += (size_t)NN * NT * 8 * 4;   // 22.4 MB
    int*  cnti  = (int*)(ws + off); off += (size_t)NN * NT * 4;       //  2.8 MB
    int*  ovfp  = (int*)(ws + off); off += (size_t)NT * NN * OVF * 4; // 33.6 MB
    char* aggb  = ws + off;                                           // remainder

    // chunk rows: fit workspace AND cap for L3 residency of the reused chunk
    size_t avail = (ws_size > off) ? (ws_size - off) : 0;
    int Nc = (int)(avail / ((size_t)NT * 256));
    Nc &= ~127;
    if (Nc < 128) Nc = 128;
    if (Nc > NCMAX) Nc = NCMAX;

    convx_k<<<(NN * DD / 8 + 255) / 256, 256, 0, stream>>>(x, (uint4*)xb);
    wconv_k<<<(NT * 128 + 3) / 4, 256, 0, stream>>>(W, WTb);
    hipMemsetAsync(cnti, 0, (size_t)NN * NT * 4, stream);
    fill_k<<<dim3(NSLAB * NPART, NT), 256, 0, stream>>>(ei, cnti, eidx8, ovfp);

    for (int c0 = 0; c0 < NN; c0 += Nc) {
        int nc = (NROWS - c0 < Nc) ? (NROWS - c0) : Nc;   // multiple of 128
        agg_k<<<nc / 4, 256, 0, stream>>>(xb, cnti, eidx8, ovfp, aggb, c0, nc);
        gemm_k<<<nc / 128, 512, 0, stream>>>(aggb, WTb, cnti, b, out, c0, nc);
    }
}

// Round 10
// 264.216 us; speedup vs baseline: 1.1877x; 1.1877x over previous
//
#include <hip/hip_runtime.h>

// SwitchGNN split pipeline (R8 single-pass + nontemporal streaming reads):
//  out = (1/7) * sum_t [ (segsum_t(x[src]) / max(cnt,1)) @ W_t + 1{cnt>0} b_t ]
// P0 convx_k: x -> bf16 rows (256B each); halves gather payload
// P1 wconv_k: W -> bf16, transposed [t][f][k], XOR-swizzled (GEMM B operand)
// P2 fill_k : bucket edges by (dst,type), XCD-partitioned dst ranges.
//             Edge reads are NONTEMPORAL so the 112MB read stream doesn't
//             evict the dirty 2.8MB/XCD scatter slice from L2 (R9: 98MB of
//             per-edge line writebacks because streaming reads thrashed L2).
// P3 agg_k  : one wave per node, all 7 types, 2-type x 2-edge (4 chains);
//             read-once index streams nontemporal, xb gather cached
// P4 gemm_k : 128-row tiles, 8 waves, K=7x128, global_load_lds(16B),
//             mfma_f32_16x16x32_bf16, bias+mean epilogue.

constexpr int NN = 100000;
constexpr int NT = 7;
constexpr int NE = 250000;
constexpr int DD = 128;
constexpr int CAP = 20;           // max tracked edges per (n,t); P(Poisson(2.5)>20)~3e-12
constexpr int OVF = CAP - 8;      // overflow slots beyond the 8 fast slots
constexpr int NROWS = ((NN + 127) / 128) * 128;   // 100096 padded rows
constexpr int NPART = 8;                          // dst partitions = XCDs
constexpr int PSIZE = (NN + NPART - 1) / NPART;   // 12500 nodes per partition
constexpr int EPB = 1024;                         // edges per fill block
constexpr int NSLAB = (NE + EPB - 1) / EPB;       // 245 slabs

typedef short bf16x8 __attribute__((ext_vector_type(8)));
typedef float f32x4 __attribute__((ext_vector_type(4)));
typedef int   i32x4 __attribute__((ext_vector_type(4)));
typedef float fltx4 __attribute__((ext_vector_type(4)));

__device__ __forceinline__ unsigned pack_bf16x2(float lo, float hi) {
    unsigned a = __float_as_uint(lo), b = __float_as_uint(hi);
    unsigned al = (a + 0x7FFFu + ((a >> 16) & 1u)) >> 16;          // RNE
    unsigned bh = (b + 0x7FFFu + ((b >> 16) & 1u)) & 0xFFFF0000u;
    return al | bh;
}

// ---------------------------------------------------------------- conv x ----
__global__ __launch_bounds__(256) void convx_k(
    const float* __restrict__ x, uint4* __restrict__ xb)
{
    int id = blockIdx.x * 256 + threadIdx.x;
    const fltx4* src = (const fltx4*)x;
    fltx4 v0 = __builtin_nontemporal_load(src + (size_t)id * 2);
    fltx4 v1 = __builtin_nontemporal_load(src + (size_t)id * 2 + 1);
    uint4 o;
    o.x = pack_bf16x2(v0[0], v0[1]);
    o.y = pack_bf16x2(v0[2], v0[3]);
    o.z = pack_bf16x2(v1[0], v1[1]);
    o.w = pack_bf16x2(v1[2], v1[3]);
    xb[id] = o;
}

// ---------------------------------------------------------------- W conv ----
// WTb[t][f][k] bf16, row=256B, granule ^= f&7. One wave per (t,f).
__global__ __launch_bounds__(256) void wconv_k(
    const float* __restrict__ W, char* __restrict__ WTb)
{
    int wid = (blockIdx.x * 256 + threadIdx.x) >> 6;
    int lane = threadIdx.x & 63;
    int t = wid >> 7, f = wid & 127;
    if (t >= NT) return;
    const float* Wt = W + (size_t)t * DD * DD;
    float w0 = Wt[(size_t)(2 * lane) * DD + f];
    float w1 = Wt[(size_t)(2 * lane + 1) * DD + f];
    int gran = (lane >> 2) ^ (f & 7);
    *(unsigned*)(WTb + (size_t)t * 32768 + f * 256 + gran * 16 + (lane & 3) * 4)
        = pack_bf16x2(w0, w1);
}

// ------------------------------------------------------------------ fill ----
// blockIdx.x = slab*8 + partition; keep only edges whose dst is in this
// partition's 1/8 range. Nontemporal edge reads: the read stream must not
// evict the partition's dirty scatter lines from L2.
__global__ __launch_bounds__(256) void fill_k(
    const int* __restrict__ ei,      // [NT][2][NE]
    int* __restrict__ cnt,           // [NN][NT], zeroed
    int* __restrict__ eidx8,         // [NN][NT][8]
    int* __restrict__ ovf)           // [NT][NN][OVF]
{
    int part = blockIdx.x & (NPART - 1);
    int slab = blockIdx.x >> 3;
    int t = blockIdx.y;
    int e0 = slab * EPB + threadIdx.x * 4;
    if (e0 >= NE) return;
    const int* p = ei + (size_t)t * 2 * NE;
    i32x4 s4 = __builtin_nontemporal_load((const i32x4*)(p + e0));
    i32x4 d4 = __builtin_nontemporal_load((const i32x4*)(p + NE + e0));
    int lo = part * PSIZE;
    int hi = lo + PSIZE;
    #pragma unroll
    for (int k = 0; k < 4; ++k) {
        int src = s4[k];
        int dst = d4[k];
        if (dst >= lo && dst < hi) {
            int pos = atomicAdd(cnt + (size_t)dst * NT + t, 1);
            if (pos < 8)        eidx8[((size_t)dst * NT + t) * 8 + pos] = src;
            else if (pos < CAP) ovf[((size_t)t * NN + dst) * OVF + (pos - 8)] = src;
        }
    }
}

// ------------------------------------------------------------- aggregate ----
// One wave per row (node n = c0 + wid). Lanes 0..6: per-type counts;
// lanes 0..55: fast-slot indices. 2 types x 2 edges = 4 gather chains in
// flight. Lane holds features 2*lane, 2*lane+1. Rows n >= NN write zeros.
__global__ __launch_bounds__(256) void agg_k(
    const char* __restrict__ xb,     // [NN][256B] bf16 rows
    const int* __restrict__ cnt,     // [NN][NT]
    const int* __restrict__ eidx8,   // [NN][NT][8]
    const int* __restrict__ ovf,     // [NT][NN][OVF]
    char* __restrict__ aggb,         // [NT][nc][256B] chunk, swizzled
    int c0, int nc)
{
    int wid = (blockIdx.x * 256 + threadIdx.x) >> 6;
    int lane = threadIdx.x & 63;
    if (wid >= nc) return;
    const int n = c0 + wid;
    const bool live = (n < NN);

    int cntv = (live && lane < NT)
             ? __builtin_nontemporal_load(cnt + (size_t)n * NT + lane) : 0;
    int idxv = (live && lane < 56)
             ? __builtin_nontemporal_load(eidx8 + (size_t)n * 56 + lane) : 0;

    int r = wid & 127;
    int gran = (lane >> 2) ^ (r & 7);            // swizzle for ds_read_b128
    char* wbase = aggb + (size_t)(wid >> 7) * 32768 + r * 256
                + gran * 16 + (lane & 3) * 4;
    const size_t tstride = (size_t)nc * 256;

    for (int tp = 0; tp < NT; tp += 2) {
        int cA = __shfl(cntv, tp);
        int cB = (tp + 1 < NT) ? __shfl(cntv, tp + 1) : 0;
        int ccA = cA < CAP ? cA : CAP;
        int ccB = cB < CAP ? cB : CAP;
        int m = ccA > ccB ? ccA : ccB;

        float a0 = 0.f, a1 = 0.f, b0 = 0.f, b1 = 0.f;
        for (int e = 0; e < m; e += 2) {         // 4 chains: 2 types x 2 edges
            unsigned vA0 = 0, vA1 = 0, vB0 = 0, vB1 = 0;
            bool gA0 = e < ccA, gA1 = e + 1 < ccA;
            bool gB0 = e < ccB, gB1 = e + 1 < ccB;
            if (gA0) {
                int s = (e < 8) ? __shfl(idxv, tp * 8 + e)
                                : __builtin_nontemporal_load(
                                      ovf + ((size_t)tp * NN + n) * OVF + (e - 8));
                vA0 = *(const unsigned*)(xb + (size_t)s * 256 + lane * 4);
            }
            if (gA1) {
                int s = (e + 1 < 8) ? __shfl(idxv, tp * 8 + e + 1)
                                    : __builtin_nontemporal_load(
                                          ovf + ((size_t)tp * NN + n) * OVF + (e - 7));
                vA1 = *(const unsigned*)(xb + (size_t)s * 256 + lane * 4);
            }
            if (gB0) {
                int s = (e < 8) ? __shfl(idxv, (tp + 1) * 8 + e)
                                : __builtin_nontemporal_load(
                                      ovf + ((size_t)(tp + 1) * NN + n) * OVF + (e - 8));
                vB0 = *(const unsigned*)(xb + (size_t)s * 256 + lane * 4);
            }
            if (gB1) {
                int s = (e + 1 < 8) ? __shfl(idxv, (tp + 1) * 8 + e + 1)
                                    : __builtin_nontemporal_load(
                                          ovf + ((size_t)(tp + 1) * NN + n) * OVF + (e - 7));
                vB1 = *(const unsigned*)(xb + (size_t)s * 256 + lane * 4);
            }
            a0 += __uint_as_float(vA0 << 16) + __uint_as_float(vA1 << 16);
            a1 += __uint_as_float(vA0 & 0xFFFF0000u) + __uint_as_float(vA1 & 0xFFFF0000u);
            b0 += __uint_as_float(vB0 << 16) + __uint_as_float(vB1 << 16);
            b1 += __uint_as_float(vB0 & 0xFFFF0000u) + __uint_as_float(vB1 & 0xFFFF0000u);
        }
        float sa = 1.0f / fmaxf((float)cA, 1.0f);   // mean folded pre-GEMM
        *(unsigned*)(wbase + (size_t)tp * tstride) = pack_bf16x2(a0 * sa, a1 * sa);
        if (tp + 1 < NT) {
            float sb = 1.0f / fmaxf((float)cB, 1.0f);
            *(unsigned*)(wbase + (size_t)(tp + 1) * tstride) = pack_bf16x2(b0 * sb, b1 * sb);
        }
    }
}

// ------------------------------------------------------------------ gemm ----
// 512 threads = 8 waves; wave w=(wy,wx): rows wy*32..+31, cols wx*64..+63.
// K-loop over 7 types (K=896, BK=128). Rows are chunk-local.
__global__ __launch_bounds__(512) void gemm_k(
    const char* __restrict__ aggb, const char* __restrict__ WTb,
    const int* __restrict__ cnt, const float* __restrict__ bias,
    float* __restrict__ out, int c0, int nc)
{
    __shared__ char sA[128 * 256];   // 32 KB
    __shared__ char sW[128 * 256];   // 32 KB
    int tid = threadIdx.x;
    int w = tid >> 6, lane = tid & 63;
    int wy = w >> 1, wx = w & 1;
    int n0 = c0 + blockIdx.x * 128;
    const size_t tstride = (size_t)nc * 256;

    f32x4 acc[2][4];
    #pragma unroll
    for (int i = 0; i < 2; ++i)
        #pragma unroll
        for (int j = 0; j < 4; ++j) acc[i][j] = (f32x4)0.0f;

    for (int t = 0; t < NT; ++t) {
        __syncthreads();   // prev MFMA readers done before restage
        const char* asrc = aggb + (size_t)t * tstride + (size_t)blockIdx.x * 32768;
        const char* wsrc = WTb + (size_t)t * 32768;
        #pragma unroll
        for (int i = 0; i < 4; ++i) {
            int ch = w * 4 + i;     // 32 chunks x 1KB each
            __builtin_amdgcn_global_load_lds(
                (const __attribute__((address_space(1))) void*)(asrc + ch * 1024 + lane * 16),
                (__attribute__((address_space(3))) void*)(sA + ch * 1024), 16, 0, 0);
            __builtin_amdgcn_global_load_lds(
                (const __attribute__((address_space(1))) void*)(wsrc + ch * 1024 + lane * 16),
                (__attribute__((address_space(3))) void*)(sW + ch * 1024), 16, 0, 0);
        }
        __syncthreads();   // compiler drains vmcnt before barrier

        #pragma unroll
        for (int c = 0; c < 4; ++c) {
            int gsel = ((c * 4 + (lane >> 4)) ^ (lane & 7)) << 4;
            bf16x8 A0 = *(const bf16x8*)(sA + (wy * 32 + (lane & 15)) * 256 + gsel);
            bf16x8 A1 = *(const bf16x8*)(sA + (wy * 32 + 16 + (lane & 15)) * 256 + gsel);
            #pragma unroll
            for (int nj = 0; nj < 4; ++nj) {
                bf16x8 B = *(const bf16x8*)(sW + (wx * 64 + nj * 16 + (lane & 15)) * 256 + gsel);
                acc[0][nj] = __builtin_amdgcn_mfma_f32_16x16x32_bf16(A0, B, acc[0][nj], 0, 0, 0);
                acc[1][nj] = __builtin_amdgcn_mfma_f32_16x16x32_bf16(A1, B, acc[1][nj], 0, 0, 0);
            }
        }
    }

    // epilogue: mean over types + per-type bias where cnt>0
    const float inv7 = 1.0f / (float)NT;
    #pragma unroll
    for (int mi = 0; mi < 2; ++mi) {
        #pragma unroll
        for (int v = 0; v < 4; ++v) {
            int n = n0 + wy * 32 + mi * 16 + (lane >> 4) * 4 + v;
            if (n >= NN) continue;
            float add[4] = {0.f, 0.f, 0.f, 0.f};
            for (int t = 0; t < NT; ++t) {
                if (cnt[(size_t)n * NT + t] > 0) {
                    #pragma unroll
                    for (int nj = 0; nj < 4; ++nj)
                        add[nj] += bias[(size_t)t * DD + wx * 64 + nj * 16 + (lane & 15)];
                }
            }
            #pragma unroll
            for (int nj = 0; nj < 4; ++nj)
                out[(size_t)n * DD + wx * 64 + nj * 16 + (lane & 15)]
                    = inv7 * (acc[mi][nj][v] + add[nj]);
        }
    }
}

// ---------------------------------------------------------------- launch ----
extern "C" void kernel_launch(void* const* d_in, const int* in_sizes, int n_in,
                              void* d_out, int out_size, void* d_ws, size_t ws_size,
                              hipStream_t stream) {
    const float* x  = (const float*)d_in[0];
    const int*   ei = (const int*)d_in[1];
    const float* W  = (const float*)d_in[2];
    const float* b  = (const float*)d_in[3];
    float* out = (float*)d_out;
    char* ws = (char*)d_ws;

    // fixed tables: 84.7 MB (layout proven R6/R8/R9)
    size_t off = 0;
    char* xb    = ws + off; off += (size_t)NN * 256;                  // 25.6 MB
    char* WTb   = ws + off; off += (size_t)NT * 128 * 256;            // 224 KB
    int*  eidx8 = (int*)(ws + off); off += (size_t)NN * NT * 8 * 4;   // 22.4 MB
    int*  cnti  = (int*)(ws + off); off += (size_t)NN * NT * 4;       //  2.8 MB
    int*  ovfp  = (int*)(ws + off); off += (size_t)NT * NN * OVF * 4; // 33.6 MB
    char* aggb  = ws + off;                                           // remainder

    // single pass when workspace allows (R9 showed chunking hurts gemm occupancy)
    size_t avail = (ws_size > off) ? (ws_size - off) : 0;
    int Nc = (int)(avail / ((size_t)NT * 256));
    Nc &= ~127;
    if (Nc < 128) Nc = 128;
    if (Nc > NROWS) Nc = NROWS;

    convx_k<<<(NN * DD / 8 + 255) / 256, 256, 0, stream>>>(x, (uint4*)xb);
    wconv_k<<<(NT * 128 + 3) / 4, 256, 0, stream>>>(W, WTb);
    hipMemsetAsync(cnti, 0, (size_t)NN * NT * 4, stream);
    fill_k<<<dim3(NSLAB * NPART, NT), 256, 0, stream>>>(ei, cnti, eidx8, ovfp);

    for (int c0 = 0; c0 < NN; c0 += Nc) {
        int nc = (NROWS - c0 < Nc) ? (NROWS - c0) : Nc;   // multiple of 128
        agg_k<<<nc / 4, 256, 0, stream>>>(xb, cnti, eidx8, ovfp, aggb, c0, nc);
        gemm_k<<<nc / 128, 512, 0, stream>>>(aggb, WTb, cnti, b, out, c0, nc);
    }
}